// Round 10
// baseline (477.405 us; speedup 1.0000x reference)
//
#include <hip/hip_runtime.h>
#include <math.h>

// (B,H,L,D) = (8,8,2048,512).  rows = B*H*L = 131072, FFT length 512.
// Identity:  Re(ifft(W . fft(x))) == ifft(Wp . fft(x)),  Wp[k] = (W[k]+conj(W[(N-k)%N]))/2
// Wp Hermitian => real result for real x; map is C-linear, so two real rows sharing a
// weight row pack as z = x1 + i*x2:  ifft(Wp.fft(z)) = out1 + i*out2 exactly.
// Inverse via forward FFT:  ifft(G) = conj(fft(conj(G)))/N  (the /N is folded into Wp).
//
// R8 (resubmitted R10; infra timeouts R8/R9): LDS-byte diet. Accounting across
// all 155-170us variants: per-tile LDS traffic was ~63KB for 4KB useful data
// (~79us/CU of LDS-pipe time at 85B/cy, same order as the 91us HBM floor) --
// the invariant resource. Cut to ~48KB:
//  - stage-1 twiddle TABLE -> registers per call (1 cos+1 sin+6 cmul; twA and
//    the only __syncthreads gone; waves fully independent)
//  - cw gate row -> 16 b64 REGISTER loads issued before FFT1 (cwb LDS gone;
//    latency covered by FFT1; compiler inserts the wait)
//  - x input -> linear global_load_lds DMA issued first (no reg-load stall,
//    no b128 staging writes); counted vmcnt(16) waits x only, cw stays in flight
//  - output restage kept (wide dwordx4 stores, R6-proven)

#define HL 16384

__device__ __forceinline__ float2 cadd(float2 a, float2 b){ return make_float2(a.x+b.x, a.y+b.y); }
__device__ __forceinline__ float2 csub(float2 a, float2 b){ return make_float2(a.x-b.x, a.y-b.y); }
__device__ __forceinline__ float2 cmul(float2 a, float2 b){ return make_float2(a.x*b.x - a.y*b.y, a.x*b.y + a.y*b.x); }

// exp(-2*pi*i*f), f in revolutions. v_sin_f32/v_cos_f32 take revolutions -> 1 inst each.
__device__ __forceinline__ float2 twiddle(float f) {
    return make_float2(__builtin_amdgcn_cosf(f), -__builtin_amdgcn_sinf(f));
}

// Compile-time ordering point only; same-wave DS ops complete in order.
__device__ __forceinline__ void lds_order() {
    __builtin_amdgcn_wave_barrier();
}

// 8-point DFT, natural order, forward sign.
__device__ __forceinline__ void fft8(float2 x[8]) {
    const float c = 0.70710678118654752f;
    float2 u0 = cadd(x[0], x[4]);
    float2 u1 = cadd(x[1], x[5]);
    float2 u2 = cadd(x[2], x[6]);
    float2 u3 = cadd(x[3], x[7]);
    float2 v0 = csub(x[0], x[4]);
    float2 t1 = csub(x[1], x[5]);
    float2 t2 = csub(x[2], x[6]);
    float2 t3 = csub(x[3], x[7]);
    float2 v1 = make_float2(c*(t1.x + t1.y), c*(t1.y - t1.x));   // * W8^1
    float2 v2 = make_float2(t2.y, -t2.x);                        // * W8^2
    float2 v3 = make_float2(c*(t3.y - t3.x), -c*(t3.x + t3.y));  // * W8^3
    float2 p0 = cadd(u0, u2), p1 = cadd(u1, u3);
    float2 q0 = csub(u0, u2), q1t = csub(u1, u3);
    float2 q1 = make_float2(q1t.y, -q1t.x);
    x[0] = cadd(p0, p1);
    x[4] = csub(p0, p1);
    x[2] = cadd(q0, q1);
    x[6] = csub(q0, q1);
    float2 r0 = cadd(v0, v2), r1 = cadd(v1, v3);
    float2 s0 = csub(v0, v2), s1t = csub(v1, v3);
    float2 s1 = make_float2(s1t.y, -s1t.x);
    x[1] = cadd(r0, r1);
    x[5] = csub(r0, r1);
    x[3] = cadd(s0, s1);
    x[7] = csub(s0, s1);
}

// 512-pt forward FFT, one wave, 8 complex per lane, AoS float2 scratch (8*72 per wave).
// Stage-1 twiddles: built in REGISTERS per call (role-dependent; 2 trans + 6 cmul).
// Stage-2 twiddles: registers tw2[j] (function of lane&7, shared by both calls).
// Input: lane with role r holds z[64*j + r] in v[j].
// Output: lane holds Z[ds(lane) + 64*j] in v[j], ds(r) = ((r&7)<<3)|(r>>3).
__device__ __forceinline__ void fft512_r(float2 v[8], int role, int lane, float2* sc,
                                         const float2 tw2[8])
{
    // ---- stage 1: radix-8 over stride 64, twiddle W512^{role*k1} ----
    fft8(v);
    {
        const float2 w1 = twiddle((float)role * (1.0f/512.0f));
        const float2 w2 = cmul(w1, w1);
        const float2 w3 = cmul(w1, w2);
        const float2 w4 = cmul(w2, w2);
        const float2 w5 = cmul(w1, w4);
        const float2 w6 = cmul(w2, w4);
        const float2 w7 = cmul(w3, w4);
        v[1] = cmul(v[1], w1);
        v[2] = cmul(v[2], w2);
        v[3] = cmul(v[3], w3);
        v[4] = cmul(v[4], w4);
        v[5] = cmul(v[5], w5);
        v[6] = cmul(v[6], w6);
        v[7] = cmul(v[7], w7);
    }
    lds_order();                     // WAR: prior reads of scratch drained (in-order pipe)
    #pragma unroll
    for (int k1 = 0; k1 < 8; ++k1) sc[k1*72 + role] = v[k1];
    lds_order();
    // ---- stage 2: 8 independent 64-pt FFTs; radix-8 over stride 8 ----
    const int k1 = lane >> 3, m2 = lane & 7;
    float2 u[8];
    #pragma unroll
    for (int m1 = 0; m1 < 8; ++m1) u[m1] = sc[k1*72 + 8*m1 + m2];
    fft8(u);
    #pragma unroll
    for (int j = 1; j < 8; ++j) u[j] = cmul(u[j], tw2[j]);
    lds_order();                     // WAR: stage-2 reads done before overwrite
    #pragma unroll
    for (int j1 = 0; j1 < 8; ++j1) sc[k1*72 + 9*j1 + m2] = u[j1];
    lds_order();
    // ---- stage 3: radix-8 over stride 1, no twiddle ----
    const int j1 = lane & 7;
    #pragma unroll
    for (int m = 0; m < 8; ++m) v[m] = sc[k1*72 + 9*j1 + m];
    fft8(v);                         // v[j2] = X[k1 + 8*j1 + 64*j2]
}

// address-space typedefs for global_load_lds
using gu32 = __attribute__((address_space(1))) const unsigned int;
using lu32 = __attribute__((address_space(3))) unsigned int;

__global__ __launch_bounds__(256, 4) void sgn_fft_diet(
    const float* __restrict__ x,
    const float* __restrict__ cw,    // (H,L,512,2)
    float* __restrict__ out)
{
    __shared__ __align__(16) float2 sc[4][8*72];   // per-wave FFT + restage scratch (18432 B)
    __shared__ __align__(16) float  xb[4][2][512]; // per-wave DMA'd input rows (16384 B)

    const int tid  = threadIdx.x;
    const int wid  = tid >> 6;       // wave id in [0,4): packed pair (batches wid, wid+4)
    const int lane = tid & 63;
    const int dsl  = ((lane & 7) << 3) | (lane >> 3);
    const int hl   = blockIdx.x;     // weight row

    const int r1 = (wid       * HL + hl) * 512;   // batch wid
    const int r2 = ((wid + 4) * HL + hl) * 512;   // batch wid+4

    // ---- 1. x DMA: first instructions; linear layout (lane*16B contract) ----
    #pragma unroll
    for (int c = 0; c < 2; ++c) {
        __builtin_amdgcn_global_load_lds((gu32*)(x + r1 + c*256 + 4*lane),
                                         (lu32*)(&xb[wid][0][c*256]), 16, 0, 0);
        __builtin_amdgcn_global_load_lds((gu32*)(x + r2 + c*256 + 4*lane),
                                         (lu32*)(&xb[wid][1][c*256]), 16, 0, 0);
    }
    __builtin_amdgcn_sched_barrier(0);   // pin: cw loads must issue AFTER the 4 DMA ops

    // ---- 2. stage-2 twiddles in registers (lane&7 only, shared by both calls) ----
    float2 tw2[8];
    {
        const int m2 = lane & 7;
        tw2[1] = twiddle((float)m2 * (1.0f/64.0f));
        tw2[2] = cmul(tw2[1], tw2[1]);
        tw2[3] = cmul(tw2[1], tw2[2]);
        tw2[4] = cmul(tw2[2], tw2[2]);
        tw2[5] = cmul(tw2[1], tw2[4]);
        tw2[6] = cmul(tw2[2], tw2[4]);
        tw2[7] = cmul(tw2[3], tw2[4]);
    }

    // ---- 3. cw gate row -> registers, issued now, consumed after FFT1 ----
    const float2* __restrict__ cw2 = (const float2*)cw;
    const int wrow = hl * 512;
    float2 wk[8], wnk[8];
    #pragma unroll
    for (int j2 = 0; j2 < 8; ++j2) {
        const int k  = dsl + 64*j2;
        const int nk = (512 - k) & 511;
        wk[j2]  = cw2[wrow + k];
        wnk[j2] = cw2[wrow + nk];
    }

    // ---- 4. wait x DMA only (4 oldest); the 16 cw loads stay in flight ----
    asm volatile("s_waitcnt vmcnt(16)" ::: "memory");

    // unpack: z = x1 + i*x2, lane r holds z[64j + r]  (b32 reads, 2/bank = free)
    float2 v[8];
    #pragma unroll
    for (int j = 0; j < 8; ++j) {
        v[j].x = xb[wid][0][64*j + lane];
        v[j].y = xb[wid][1][64*j + lane];
    }

    float2* scw = &sc[wid][0];
    fft512_r(v, lane, lane, scw, tw2);

    // ---- 5. gate: G = Wp * Z (Wp pre-scaled by 1/512), then conj ----
    {
        const float hs = 0.5f / 512.0f;
        #pragma unroll
        for (int j2 = 0; j2 < 8; ++j2) {
            const float2 wp = make_float2(hs*(wk[j2].x + wnk[j2].x),
                                          hs*(wk[j2].y - wnk[j2].y));
            const float2 g  = cmul(wp, v[j2]);
            v[j2] = make_float2(g.x, -g.y);
        }
    }

    fft512_r(v, dsl, lane, scw, tw2);

    // ---- 6. output restage: OD[k]=(out1[k],out2[k]) -> 4 dwordx4 stores ----
    lds_order();                     // FFT2 stage-3 sc reads drained (in-order)
    {
        float2* OD = scw;
        #pragma unroll
        for (int j2 = 0; j2 < 8; ++j2)
            OD[dsl + 64*j2] = make_float2(v[j2].x, -v[j2].y);   // b64, 4/bank = min
    }
    lds_order();
    #pragma unroll
    for (int c = 0; c < 2; ++c) {
        const float2* OD = scw;
        const float4 p = *(const float4*)&OD[4*lane + 256*c];
        const float4 q = *(const float4*)&OD[4*lane + 256*c + 2];
        *(float4*)(out + r1 + 4*lane + 256*c) = make_float4(p.x, p.z, q.x, q.z);
        *(float4*)(out + r2 + 4*lane + 256*c) = make_float4(p.y, p.w, q.y, q.w);
    }
}

extern "C" void kernel_launch(void* const* d_in, const int* in_sizes, int n_in,
                              void* d_out, int out_size, void* d_ws, size_t ws_size,
                              hipStream_t stream) {
    const float* x  = (const float*)d_in[0];   // (B,H,L,D) fp32
    // d_in[1] = mask, unused
    const float* cw = (const float*)d_in[2];   // (H,L,D,2) fp32
    float* out = (float*)d_out;

    sgn_fft_diet<<<dim3(HL), dim3(256), 0, stream>>>(x, cw, out);
}